// Round 1
// 88.620 us; speedup vs baseline: 1.0136x; 1.0136x over previous
//
#include <hip/hip_runtime.h>

// Problem constants (reference: B, LQ, LK, H = 4, 512, 512, 128)
#define B_   4
#define LQ_  512
#define LK_  512
#define H_   128

#define RPB  4      // rows per block in projection kernel
#define QPT  4      // q-values per thread in score kernel (was 8: 2x more waves)
#define KTH  256    // threads per block (one k per thread) in score kernel

// ws layout: Eq [B*LQ*H] | EkT [B*LK*H] | base [1]
//
// Math: tanh(s) = 1 - 2/(e^{2s}+1);  e^{2s} = Eq*Ek with
//   Eq = exp2(C*qU), Ek = exp2(C*(kT+b)), C = 2*log2(e).
// out[b,q,k] = (sum_h w_h + w_bias) - 2 * sum_h w_h / (Eq*Ek + 1)
//
// EkT is stored k-interleaved for coalescing in the score kernel:
//   EkT[b][h>>2][k][h&3]  (4 consecutive h's for one k are 16 B contiguous;
//   adjacent k's are adjacent 16 B units -> lane stride 16 B = perfect
//   dwordx4 coalescing, 1 KB/instruction).

// ---------------------------------------------------------------------------
// Kernel 1: projections + exp2 epilogue. blockIdx.y: 0=q-side, 1=k-side.
// One block = RPB rows, 128 threads over h. M reads coalesced; X reads
// wave-uniform -> scalar loads. k-side writes the interleaved EkT layout
// (scattered dword stores — negligible, write-combined in L2).
// ---------------------------------------------------------------------------
__global__ __launch_bounds__(128) void proj_kernel(
    const float* __restrict__ queries, const float* __restrict__ keys,
    const float* __restrict__ U, const float* __restrict__ T,
    const float* __restrict__ bvec, const float* __restrict__ w,
    const float* __restrict__ wb,
    float* __restrict__ Eq, float* __restrict__ EkT, float* __restrict__ base)
{
    const int side = blockIdx.y;  // 0 = q-side, 1 = k-side
    const float* __restrict__ X = side ? keys : queries;
    const float* __restrict__ M = side ? T : U;

    const int t  = threadIdx.x;          // h index, 0..127
    const int r0 = blockIdx.x * RPB;     // first row of this block (global)

    // one thread computes base = w_bias + sum(w); overlapped with the GEMM
    if (side == 1 && blockIdx.x == 0 && t == 0) {
        float s = wb[0];
        for (int h = 0; h < H_; ++h) s += w[h];
        base[0] = s;
    }

    float acc[RPB];
#pragma unroll
    for (int i = 0; i < RPB; ++i) acc[i] = 0.f;

#pragma unroll 8
    for (int d = 0; d < H_; ++d) {
        float m = M[d * H_ + t];                      // coalesced across lanes
#pragma unroll
        for (int i = 0; i < RPB; ++i)                 // uniform addr -> s_load
            acc[i] = fmaf(X[(size_t)(r0 + i) * H_ + d], m, acc[i]);
    }

    const float C = 2.8853900817779268f;  // 2 * log2(e)
    if (side) {
        const int b     = r0 / LK_;       // RPB divides LK_, so one b/block
        const int kbase = r0 % LK_;
        const float bb  = bvec[t];
        float* __restrict__ y = EkT + (size_t)b * H_ * LK_
                              + (size_t)(t >> 2) * (LK_ * 4) + (t & 3);
#pragma unroll
        for (int i = 0; i < RPB; ++i)
            y[(size_t)(kbase + i) * 4] =
                __builtin_amdgcn_exp2f(C * (acc[i] + bb));
    } else {
#pragma unroll
        for (int i = 0; i < RPB; ++i)
            Eq[(size_t)(r0 + i) * H_ + t] =
                __builtin_amdgcn_exp2f(C * acc[i]);
    }
}

// ---------------------------------------------------------------------------
// Kernel 2: rational-pair reduction, 1 v_rcp_f32 per 4 h:
//   sum_i w_i/x_i over 4 terms = (n01*d23 + n23*d01) / (d01*d23),
//   x_i = fma(Eq_i, Ek_i, 1).  13 plain VALU + 1 trans per 4 elements.
// Thread owns one k; ek4 chunk (4 h, one coalesced dwordx4 from EkT) is
// reused across QPT=4 q-rows. Eq/w reads wave-uniform -> s_load.
//
// QPT=4 (was 8): grid 1024 blocks -> 16 waves/CU (4/SIMD) for latency
// hiding; unroll 4 keeps 4 independent dwordx4 loads in flight per wave.
// Per-output arithmetic order identical to QPT=8 version (bit-exact).
// ---------------------------------------------------------------------------
__global__ __launch_bounds__(KTH) void score_kernel(
    const float* __restrict__ Eq, const float* __restrict__ EkT,
    const float* __restrict__ w, const float* __restrict__ base_p,
    float* __restrict__ out)
{
    const int b  = blockIdx.z;
    const int q0 = blockIdx.y * QPT;
    const int k  = blockIdx.x * KTH + threadIdx.x;

    const float* __restrict__ eqr = Eq + ((size_t)b * LQ_ + q0) * H_;
    const float* __restrict__ ekT = EkT + (size_t)b * H_ * LK_ + (size_t)k * 4;

    float acc[QPT];
#pragma unroll
    for (int i = 0; i < QPT; ++i) acc[i] = 0.f;

#pragma unroll 4
    for (int c = 0; c < H_; c += 4) {
        // lane stride 16 B -> one fully-coalesced global_load_dwordx4
        float4 ek4 = *(const float4*)(ekT + (size_t)(c >> 2) * (LK_ * 4));
        float w0 = w[c], w1 = w[c + 1], w2 = w[c + 2], w3 = w[c + 3];
#pragma unroll
        for (int q = 0; q < QPT; ++q) {
            const float* eq = eqr + q * H_ + c;          // uniform -> s_load
            float x0 = fmaf(eq[0], ek4.x, 1.f);
            float x1 = fmaf(eq[1], ek4.y, 1.f);
            float x2 = fmaf(eq[2], ek4.z, 1.f);
            float x3 = fmaf(eq[3], ek4.w, 1.f);
            float d01 = x0 * x1;
            float d23 = x2 * x3;
            float n01 = fmaf(w1, x0, w0 * x1);
            float n23 = fmaf(w3, x2, w2 * x3);
            float num = fmaf(n23, d01, n01 * d23);
            float den = d01 * d23;
            acc[q] = fmaf(num, __builtin_amdgcn_rcpf(den), acc[q]);
        }
    }

    const float base = base_p[0];                        // uniform -> s_load
#pragma unroll
    for (int q = 0; q < QPT; ++q)
        out[((size_t)b * LQ_ + q0 + q) * LK_ + k] = fmaf(-2.f, acc[q], base);
}

// ---------------------------------------------------------------------------
extern "C" void kernel_launch(void* const* d_in, const int* in_sizes, int n_in,
                              void* d_out, int out_size, void* d_ws, size_t ws_size,
                              hipStream_t stream)
{
    const float* queries = (const float*)d_in[0];
    const float* keys    = (const float*)d_in[1];
    const float* U       = (const float*)d_in[2];
    const float* T       = (const float*)d_in[3];
    const float* bvec    = (const float*)d_in[4];
    const float* w       = (const float*)d_in[5];
    const float* wb      = (const float*)d_in[6];
    float* out = (float*)d_out;

    float* Eq   = (float*)d_ws;                        // B*LQ*H fp32 = 1 MB
    float* EkT  = Eq + (size_t)B_ * LQ_ * H_;          // B*LK*H fp32 = 1 MB
    float* base = EkT + (size_t)B_ * LK_ * H_;         // 1 float

    proj_kernel<<<dim3((B_ * LQ_) / RPB, 2), 128, 0, stream>>>(
        queries, keys, U, T, bvec, w, wb, Eq, EkT, base);

    score_kernel<<<dim3(LK_ / KTH, LQ_ / QPT, B_), KTH, 0, stream>>>(
        Eq, EkT, w, base, out);
}